// Round 1
// baseline (731.340 us; speedup 1.0000x reference)
//
#include <hip/hip_runtime.h>

// Conv2d 3x3 VALID, NCHW/OIHW, fp32, as implicit GEMM:
//   C[cout][sp] = sum_k A[cout][k] * B[k][sp]
//   A = K flat (128 x 576), B[k][sp] = X[n][c][oh+kh][ow+kw]
// M = 128 (all couts in one block), N = 387200 spatial, K = 576.
// Tile: BM=128 x BN=128 x BK=8, 256 threads, 8x8 register tile/thread.

#define BN 128
#define BM 128
#define BK 8
#define TM 8
#define TN 8

constexpr int C_IN = 64, H = 112, W = 112;
constexpr int COUT = 128, OH = 110, OW = 110;
constexpr int NIMG = 32;
constexpr int KTOT = C_IN * 9;          // 576
constexpr int OSP = OH * OW;            // 12100
constexpr int SPTOT = NIMG * OSP;       // 387200 = 128 * 3025 (no tail)
constexpr int IMG_STRIDE = C_IN * H * W;
constexpr int CH_STRIDE = H * W;        // 12544
constexpr int LDA = BM + 4;             // LDS pad: breaks pow-2 bank strides
constexpr int LDB = BN + 4;

__global__ __launch_bounds__(256, 4)
void conv_igemm_f32(const float* __restrict__ X,
                    const float* __restrict__ Kw,
                    float* __restrict__ Out)
{
    __shared__ float As[BK][LDA];
    __shared__ float Bs[BK][LDB];
    __shared__ int koff[KTOT];          // X-offset per k: c*12544 + kh*112 + kw

    const int t = threadIdx.x;

    // Build the k -> X-offset table once per block (576 ints).
    for (int k = t; k < KTOT; k += 256) {
        int c = k / 9, r = k - c * 9;
        int kh = r / 3, kw = r - kh * 3;
        koff[k] = c * CH_STRIDE + kh * W + kw;
    }

    const int spBase = blockIdx.x * BN;

    // B staging: thread t loads 4 k-slots for one sp column.
    const int ldb_sp = t & 127;
    const int ldb_k0 = (t >> 7) * 4;
    {
        // per-thread spatial base, computed once
    }
    const int spg  = spBase + ldb_sp;
    const int nimg = spg / OSP;
    const int rsp  = spg - nimg * OSP;
    const int oh   = rsp / OW;
    const int ow   = rsp - oh * OW;
    const float* Xb = X + (size_t)nimg * IMG_STRIDE + oh * W + ow;

    // A staging: thread t loads one float4 (row = t>>1, k4 = (t&1)*4).
    const int lda_m = t >> 1;
    const int lda_k = (t & 1) * 4;
    const float* Ab = Kw + (size_t)lda_m * KTOT + lda_k;

    // Compute mapping: ty -> contiguous 8 couts, tx -> 8 strided sp (stride 16).
    const int ty = t >> 4;   // 0..15
    const int tx = t & 15;   // 0..15

    float acc[TM][TN];
#pragma unroll
    for (int i = 0; i < TM; i++)
#pragma unroll
        for (int j = 0; j < TN; j++) acc[i][j] = 0.f;

    __syncthreads();  // koff table ready

    for (int kt = 0; kt < KTOT; kt += BK) {
        // ---- stage ----
        const float4 a4 = *reinterpret_cast<const float4*>(Ab + kt);
        const float b0 = Xb[koff[kt + ldb_k0 + 0]];
        const float b1 = Xb[koff[kt + ldb_k0 + 1]];
        const float b2 = Xb[koff[kt + ldb_k0 + 2]];
        const float b3 = Xb[koff[kt + ldb_k0 + 3]];
        As[lda_k + 0][lda_m] = a4.x;
        As[lda_k + 1][lda_m] = a4.y;
        As[lda_k + 2][lda_m] = a4.z;
        As[lda_k + 3][lda_m] = a4.w;
        Bs[ldb_k0 + 0][ldb_sp] = b0;
        Bs[ldb_k0 + 1][ldb_sp] = b1;
        Bs[ldb_k0 + 2][ldb_sp] = b2;
        Bs[ldb_k0 + 3][ldb_sp] = b3;
        __syncthreads();

        // ---- compute ----
#pragma unroll
        for (int kk = 0; kk < BK; kk++) {
            float a[TM], b[TN];
            const float4 alo = *reinterpret_cast<const float4*>(&As[kk][ty * 8]);
            const float4 ahi = *reinterpret_cast<const float4*>(&As[kk][ty * 8 + 4]);
            a[0] = alo.x; a[1] = alo.y; a[2] = alo.z; a[3] = alo.w;
            a[4] = ahi.x; a[5] = ahi.y; a[6] = ahi.z; a[7] = ahi.w;
#pragma unroll
            for (int j = 0; j < TN; j++) b[j] = Bs[kk][tx + j * 16];
#pragma unroll
            for (int i = 0; i < TM; i++)
#pragma unroll
                for (int j = 0; j < TN; j++)
                    acc[i][j] = fmaf(a[i], b[j], acc[i][j]);
        }
        __syncthreads();
    }

    // ---- store: coalesced scalar stores (lanes consecutive in sp) ----
#pragma unroll
    for (int j = 0; j < TN; j++) {
        const int spg2 = spBase + tx + j * 16;
        const int n2 = spg2 / OSP;
        const int r2 = spg2 - n2 * OSP;
        float* Ob = Out + (size_t)n2 * (COUT * OSP) + r2;
#pragma unroll
        for (int i = 0; i < TM; i++) {
            const int cout = ty * 8 + i;
            Ob[(size_t)cout * OSP] = acc[i][j];
        }
    }
}

extern "C" void kernel_launch(void* const* d_in, const int* in_sizes, int n_in,
                              void* d_out, int out_size, void* d_ws, size_t ws_size,
                              hipStream_t stream) {
    const float* X  = (const float*)d_in[0];
    const float* Kw = (const float*)d_in[1];
    float* Out = (float*)d_out;
    dim3 grid(SPTOT / BN);   // 3025, exact
    conv_igemm_f32<<<grid, 256, 0, stream>>>(X, Kw, Out);
}

// Round 3
// 213.864 us; speedup vs baseline: 3.4196x; 3.4196x over previous
//
#include <hip/hip_runtime.h>

// Conv2d 3x3 VALID (NCHW/OIHW, fp32) as implicit GEMM with bf16-split MFMA.
//   C[cout][sp] = sum_k A[cout][k] * B[k][sp],  K = 576, M = 128, N = 387200
//   fp32 emulated as 2-way bf16 split: C = Ah*Bh + Ah*Bl + Al*Bh  (lo*lo dropped, ~2^-16 rel)
// Tile: 128(cout) x 128(sp) x BK=32, 256 threads = 4 waves, each wave 64x64
// (4x4 fragments of mfma_f32_16x16x32_bf16, 48 MFMA per K-step per wave).

typedef __attribute__((ext_vector_type(8))) short  bf16x8;
typedef __attribute__((ext_vector_type(8))) ushort u16x8;
typedef __attribute__((ext_vector_type(4))) float  f32x4;

constexpr int C_IN = 64, H = 112, W = 112;
constexpr int COUT = 128, OH = 110, OW = 110;
constexpr int NIMG = 32;
constexpr int KTOT = C_IN * 9;          // 576
constexpr int OSP  = OH * OW;           // 12100
constexpr int SPTOT = NIMG * OSP;       // 387200 = 3025 * 128
constexpr int IMG_STRIDE = C_IN * H * W;
constexpr int CH_STRIDE  = H * W;       // 12544
constexpr int BK  = 32;
constexpr int LDR = 40;                 // padded LDS row (ushorts): 80B stride -> 2-way banks (free)

__global__ __launch_bounds__(256, 2)
void conv_igemm_mfma(const float* __restrict__ X,
                     const float* __restrict__ Kw,
                     float* __restrict__ Out)
{
    __shared__ ushort AsH[128 * LDR], AsL[128 * LDR];
    __shared__ ushort BsH[128 * LDR], BsL[128 * LDR];
    __shared__ int koff[KTOT];

    const int t = threadIdx.x;

    for (int k = t; k < KTOT; k += 256) {
        int c = k / 9, r = k - c * 9;
        int kh = r / 3, kw = r - kh * 3;
        koff[k] = c * CH_STRIDE + kh * W + kw;
    }

    const int spBase = blockIdx.x * 128;

    // ---- staging mapping: col = t&127 (cout for A / sp for B), kc = t>>7 selects k-half ----
    const int col  = t & 127;
    const int kc16 = (t >> 7) * 16;

    const int spg  = spBase + col;
    const int nimg = spg / OSP;
    const int rsp  = spg - nimg * OSP;
    const int oh   = rsp / OW;
    const int ow   = rsp - oh * OW;
    const float* Xb = X + (size_t)nimg * IMG_STRIDE + oh * W + ow;
    const float* Ab = Kw + (size_t)col * KTOT + kc16;

    // ---- compute mapping: 4 waves in 2x2, each 64x64 ----
    const int lane = t & 63;
    const int wv   = t >> 6;
    const int wr   = wv >> 1;          // 0/1: cout-half
    const int wc   = wv & 1;           // 0/1: sp-half
    const int frow = lane & 15;
    const int kq   = lane >> 4;        // 0..3: k-chunk of 8
    const int aoff = (wr * 64 + frow) * LDR + kq * 8;
    const int boff = (wc * 64 + frow) * LDR + kq * 8;

    f32x4 acc[4][4];
#pragma unroll
    for (int i = 0; i < 4; i++)
#pragma unroll
        for (int j = 0; j < 4; j++) acc[i][j] = (f32x4){0.f, 0.f, 0.f, 0.f};

    __syncthreads();   // koff ready

    float aR[16], bR[16];

#define LOAD_TILE(KT)                                                          \
    {                                                                          \
        const float4* Ap = (const float4*)(Ab + (KT));                         \
        *(float4*)&aR[0]  = Ap[0];                                             \
        *(float4*)&aR[4]  = Ap[1];                                             \
        *(float4*)&aR[8]  = Ap[2];                                             \
        *(float4*)&aR[12] = Ap[3];                                             \
        _Pragma("unroll")                                                      \
        for (int jj = 0; jj < 16; jj++) bR[jj] = Xb[koff[(KT) + kc16 + jj]];   \
    }

    LOAD_TILE(0);

#pragma unroll 1
    for (int kt = 0; kt < KTOT; kt += BK) {
        // ---- split current regs to bf16 hi/lo and store to LDS ----
        {
            ushort ha[16], la[16], hb[16], lb[16];
#pragma unroll
            for (int e = 0; e < 16; e++) {
                uint xa = __float_as_uint(aR[e]);
                uint hba = xa & 0xFFFF0000u;
                float fla = aR[e] - __uint_as_float(hba);
                ha[e] = (ushort)(hba >> 16);
                la[e] = (ushort)(__float_as_uint(fla) >> 16);
                uint xb = __float_as_uint(bR[e]);
                uint hbb = xb & 0xFFFF0000u;
                float flb = bR[e] - __uint_as_float(hbb);
                hb[e] = (ushort)(hbb >> 16);
                lb[e] = (ushort)(__float_as_uint(flb) >> 16);
            }
            const int sidx = col * LDR + kc16;
            u16x8 v;
#pragma unroll
            for (int e = 0; e < 8; e++) v[e] = ha[e];
            *reinterpret_cast<u16x8*>(&AsH[sidx]) = v;
#pragma unroll
            for (int e = 0; e < 8; e++) v[e] = ha[8 + e];
            *reinterpret_cast<u16x8*>(&AsH[sidx + 8]) = v;
#pragma unroll
            for (int e = 0; e < 8; e++) v[e] = la[e];
            *reinterpret_cast<u16x8*>(&AsL[sidx]) = v;
#pragma unroll
            for (int e = 0; e < 8; e++) v[e] = la[8 + e];
            *reinterpret_cast<u16x8*>(&AsL[sidx + 8]) = v;
#pragma unroll
            for (int e = 0; e < 8; e++) v[e] = hb[e];
            *reinterpret_cast<u16x8*>(&BsH[sidx]) = v;
#pragma unroll
            for (int e = 0; e < 8; e++) v[e] = hb[8 + e];
            *reinterpret_cast<u16x8*>(&BsH[sidx + 8]) = v;
#pragma unroll
            for (int e = 0; e < 8; e++) v[e] = lb[e];
            *reinterpret_cast<u16x8*>(&BsL[sidx]) = v;
#pragma unroll
            for (int e = 0; e < 8; e++) v[e] = lb[8 + e];
            *reinterpret_cast<u16x8*>(&BsL[sidx + 8]) = v;
        }
        __syncthreads();

        // ---- prefetch next tile into regs (overlaps with MFMA below) ----
        if (kt + BK < KTOT) LOAD_TILE(kt + BK);

        // ---- MFMA on staged tile ----
        {
            bf16x8 ah[4], al[4], bh[4], bl[4];
#pragma unroll
            for (int i = 0; i < 4; i++) {
                ah[i] = *reinterpret_cast<const bf16x8*>(&AsH[aoff + i * 16 * LDR]);
                al[i] = *reinterpret_cast<const bf16x8*>(&AsL[aoff + i * 16 * LDR]);
            }
#pragma unroll
            for (int j = 0; j < 4; j++) {
                bh[j] = *reinterpret_cast<const bf16x8*>(&BsH[boff + j * 16 * LDR]);
                bl[j] = *reinterpret_cast<const bf16x8*>(&BsL[boff + j * 16 * LDR]);
            }
#pragma unroll
            for (int i = 0; i < 4; i++)
#pragma unroll
                for (int j = 0; j < 4; j++) {
                    acc[i][j] = __builtin_amdgcn_mfma_f32_16x16x32_bf16(ah[i], bh[j], acc[i][j], 0, 0, 0);
                    acc[i][j] = __builtin_amdgcn_mfma_f32_16x16x32_bf16(ah[i], bl[j], acc[i][j], 0, 0, 0);
                    acc[i][j] = __builtin_amdgcn_mfma_f32_16x16x32_bf16(al[i], bh[j], acc[i][j], 0, 0, 0);
                }
        }
        __syncthreads();
    }
#undef LOAD_TILE

    // ---- store: D frag (i,j): cout = wr*64+i*16+kq*4+r, sp = spBase+wc*64+j*16+frow ----
#pragma unroll
    for (int j = 0; j < 4; j++) {
        const int sp2 = spBase + wc * 64 + j * 16 + frow;
        const int n2  = sp2 / OSP;
        const int r2  = sp2 - n2 * OSP;
        float* Ob = Out + (size_t)n2 * (COUT * OSP) + r2;
#pragma unroll
        for (int i = 0; i < 4; i++) {
            const int cbase = wr * 64 + i * 16 + kq * 4;
#pragma unroll
            for (int r = 0; r < 4; r++)
                Ob[(size_t)(cbase + r) * OSP] = acc[i][j][r];
        }
    }
}

extern "C" void kernel_launch(void* const* d_in, const int* in_sizes, int n_in,
                              void* d_out, int out_size, void* d_ws, size_t ws_size,
                              hipStream_t stream) {
    const float* X  = (const float*)d_in[0];
    const float* Kw = (const float*)d_in[1];
    float* Out = (float*)d_out;
    dim3 grid(SPTOT / 128);   // 3025, exact
    conv_igemm_mfma<<<grid, 256, 0, stream>>>(X, Kw, Out);
}

// Round 5
// 195.485 us; speedup vs baseline: 3.7412x; 1.0940x over previous
//
#include <hip/hip_runtime.h>

// Conv2d 3x3 VALID (NCHW/OIHW, fp32) as implicit GEMM, single-term fp16 MFMA.
//   C[cout][sp] = sum_k A[cout][k]*B[k][sp], K=576, M=128, N=387200
//   fp16 inputs (RTZ convert), fp32 accumulate: max err ~1e-3 << passing absmax.
// Tile: 128(cout) x 128(sp) x BK=32, 256 thr = 4 waves (2x2), wave=64x64
// = 2x2 frags of mfma_f32_32x32x16_f16 x 2 k-halves = 8 MFMA/K-step/wave.

typedef __attribute__((ext_vector_type(8)))  _Float16 f16x8;
typedef __attribute__((ext_vector_type(16))) float    f32x16;

constexpr int C_IN = 64, H = 112, W = 112;
constexpr int COUT = 128, OH = 110, OW = 110;
constexpr int NIMG = 32;
constexpr int KTOT = C_IN * 9;          // 576
constexpr int OSP  = OH * OW;           // 12100
constexpr int SPTOT = NIMG * OSP;       // 387200 = 3025 * 128
constexpr int IMG_STRIDE = C_IN * H * W;
constexpr int CH_STRIDE  = H * W;       // 12544
constexpr int BK  = 32;
constexpr int LDR = 40;                 // fp16 units; 80B row stride -> 2-way banks (free), 16B aligned

__device__ __forceinline__ uint pkrtz_u32(float lo, float hi) {
    union { __fp16 __attribute__((ext_vector_type(2))) h; uint u; } c;
    c.h = __builtin_amdgcn_cvt_pkrtz(lo, hi);
    return c.u;
}

__global__ __launch_bounds__(256, 3)
void conv_igemm_f16(const float* __restrict__ X,
                    const float* __restrict__ Kw,
                    float* __restrict__ Out)
{
    __shared__ __align__(16) _Float16 As[128 * LDR];
    __shared__ __align__(16) _Float16 Bs[128 * LDR];
    __shared__ int koff[KTOT];

    const int t = threadIdx.x;

    for (int k = t; k < KTOT; k += 256) {
        int c = k / 9, r = k - c * 9;
        int kh = r / 3, kw = r - kh * 3;
        koff[k] = c * CH_STRIDE + kh * W + kw;
    }

    // XCD-bijective block swizzle (m204): nwg=3025, q=378, r=1.
    const int nwg = gridDim.x;
    const int q8 = nwg >> 3, r8 = nwg & 7;
    const int xcd = blockIdx.x & 7, idx8 = blockIdx.x >> 3;
    const int bid = (xcd < r8 ? xcd * (q8 + 1) : r8 * (q8 + 1) + (xcd - r8) * q8) + idx8;

    const int spBase = bid * 128;

    // ---- staging mapping: col = t&127 (cout for A / sp for B), kc16 = k-half ----
    const int col  = t & 127;
    const int kc16 = (t >> 7) * 16;

    const int spg  = spBase + col;
    const int nimg = spg / OSP;
    const int rsp  = spg - nimg * OSP;
    const int oh   = rsp / OW;
    const int ow   = rsp - oh * OW;
    const float* Xb = X + (size_t)nimg * IMG_STRIDE + oh * W + ow;
    const float* Ab = Kw + (size_t)col * KTOT + kc16;

    // ---- compute mapping: 4 waves 2x2, each 64x64, 32x32 fragments ----
    const int lane  = t & 63;
    const int wv    = t >> 6;
    const int wr    = wv >> 1;         // cout half
    const int wc    = wv & 1;          // sp half
    const int frow  = lane & 31;
    const int khalf = lane >> 5;       // 0/1: which 8-of-16 k
    const int aoff  = (wr * 64 + frow) * LDR + khalf * 8;
    const int boff  = (wc * 64 + frow) * LDR + khalf * 8;

    f32x16 acc[2][2];
#pragma unroll
    for (int i = 0; i < 2; i++)
#pragma unroll
        for (int j = 0; j < 2; j++)
#pragma unroll
            for (int e = 0; e < 16; e++) acc[i][j][e] = 0.f;

    __syncthreads();   // koff ready

    float aR[16], bR[16];

#define LOAD_TILE(KT)                                                          \
    {                                                                          \
        const float4* Ap = (const float4*)(Ab + (KT));                         \
        *(float4*)&aR[0]  = Ap[0];                                             \
        *(float4*)&aR[4]  = Ap[1];                                             \
        *(float4*)&aR[8]  = Ap[2];                                             \
        *(float4*)&aR[12] = Ap[3];                                             \
        _Pragma("unroll")                                                      \
        for (int jj = 0; jj < 16; jj++) bR[jj] = Xb[koff[(KT) + kc16 + jj]];   \
    }

    LOAD_TILE(0);

    union P8 { uint u[4]; f16x8 v; };

#pragma unroll 1
    for (int kt = 0; kt < KTOT; kt += BK) {
        // ---- convert current regs to fp16 (RTZ pack, 2 elems/inst) ----
        P8 a0, a1, b0, b1;
#pragma unroll
        for (int p = 0; p < 4; p++) {
            a0.u[p] = pkrtz_u32(aR[2 * p],     aR[2 * p + 1]);
            a1.u[p] = pkrtz_u32(aR[8 + 2 * p], aR[8 + 2 * p + 1]);
            b0.u[p] = pkrtz_u32(bR[2 * p],     bR[2 * p + 1]);
            b1.u[p] = pkrtz_u32(bR[8 + 2 * p], bR[8 + 2 * p + 1]);
        }
        const int sidx = col * LDR + kc16;
        *reinterpret_cast<f16x8*>(&As[sidx])     = a0.v;
        *reinterpret_cast<f16x8*>(&As[sidx + 8]) = a1.v;
        *reinterpret_cast<f16x8*>(&Bs[sidx])     = b0.v;
        *reinterpret_cast<f16x8*>(&Bs[sidx + 8]) = b1.v;
        __syncthreads();

        // ---- prefetch next tile into regs (overlaps MFMA) ----
        if (kt + BK < KTOT) LOAD_TILE(kt + BK);

        // ---- MFMA ----
#pragma unroll
        for (int kk = 0; kk < 2; kk++) {
            f16x8 af0 = *reinterpret_cast<const f16x8*>(&As[aoff + kk * 16]);
            f16x8 af1 = *reinterpret_cast<const f16x8*>(&As[aoff + 32 * LDR + kk * 16]);
            f16x8 bf0 = *reinterpret_cast<const f16x8*>(&Bs[boff + kk * 16]);
            f16x8 bf1 = *reinterpret_cast<const f16x8*>(&Bs[boff + 32 * LDR + kk * 16]);
            acc[0][0] = __builtin_amdgcn_mfma_f32_32x32x16_f16(af0, bf0, acc[0][0], 0, 0, 0);
            acc[0][1] = __builtin_amdgcn_mfma_f32_32x32x16_f16(af0, bf1, acc[0][1], 0, 0, 0);
            acc[1][0] = __builtin_amdgcn_mfma_f32_32x32x16_f16(af1, bf0, acc[1][0], 0, 0, 0);
            acc[1][1] = __builtin_amdgcn_mfma_f32_32x32x16_f16(af1, bf1, acc[1][1], 0, 0, 0);
        }
        __syncthreads();
    }
#undef LOAD_TILE

    // ---- store: D(32x32): col = lane&31, row = (reg&3) + 8*(reg>>2) + 4*khalf ----
#pragma unroll
    for (int j = 0; j < 2; j++) {
        const int sp2 = spBase + wc * 64 + j * 32 + frow;
        const int n2  = sp2 / OSP;
        const int r2  = sp2 - n2 * OSP;
        float* Ob = Out + (size_t)n2 * (COUT * OSP) + r2;
#pragma unroll
        for (int i = 0; i < 2; i++) {
            const int cbase = wr * 64 + i * 32 + 4 * khalf;
#pragma unroll
            for (int reg = 0; reg < 16; reg++) {
                const int crow = cbase + (reg & 3) + 8 * (reg >> 2);
                Ob[(size_t)crow * OSP] = acc[i][j][reg];
            }
        }
    }
}

extern "C" void kernel_launch(void* const* d_in, const int* in_sizes, int n_in,
                              void* d_out, int out_size, void* d_ws, size_t ws_size,
                              hipStream_t stream) {
    const float* X  = (const float*)d_in[0];
    const float* Kw = (const float*)d_in[1];
    float* Out = (float*)d_out;
    dim3 grid(SPTOT / 128);   // 3025, exact
    conv_igemm_f16<<<grid, 256, 0, stream>>>(X, Kw, Out);
}

// Round 6
// 145.396 us; speedup vs baseline: 5.0300x; 1.3445x over previous
//
#include <hip/hip_runtime.h>

// Conv2d 3x3 VALID (NCHW/OIHW, fp32) as implicit GEMM, fp16 MFMA, v2.
//   C[cout][sp] = sum_k A[cout][k]*B[k][sp], K=576, M=128, N=387200
// Changes vs v1 (215us, all pipes <16% busy -> latency-bound):
//   BK=64 (9 steps, 16 MFMA/step/wave), LDS double-buffer w/ single barrier,
//   A pre-packed fp16 in ws (frag-native, L2-resident, no A staging),
//   B LDS stride 68 (2-way banks = free), koff read as int4.

typedef __attribute__((ext_vector_type(8)))  _Float16 f16x8;
typedef __attribute__((ext_vector_type(16))) float    f32x16;

constexpr int C_IN = 64, H = 112, W = 112;
constexpr int COUT = 128, OH = 110, OW = 110;
constexpr int NIMG = 32;
constexpr int KTOT = C_IN * 9;          // 576
constexpr int OSP  = OH * OW;           // 12100
constexpr int SPTOT = NIMG * OSP;       // 387200 = 3025 * 128
constexpr int IMG_STRIDE = C_IN * H * W;
constexpr int CH_STRIDE  = H * W;       // 12544
constexpr int BK  = 64;
constexpr int NSTEP = KTOT / BK;        // 9
constexpr int LDR = 68;                 // fp16 units; 136B rows -> start-bank stride 34 = 2-way (free)

__device__ __forceinline__ uint pkrtz_u32(float lo, float hi) {
    union { __fp16 __attribute__((ext_vector_type(2))) h; uint u; } c;
    c.h = __builtin_amdgcn_cvt_pkrtz(lo, hi);
    return c.u;
}

// Pack A to fp16, frag-native: A16[koct][cout][j] = (f16)Kw[cout][koct*8+j].
// A-frag load for (koct,cout): 8 contiguous fp16 = 16B; lanes 0..31 read
// consecutive cout -> 512B contiguous per half-wave. 147KB total, L2-resident.
__global__ void prep_a(const float* __restrict__ Kw, _Float16* __restrict__ A16) {
    int idx = blockIdx.x * 256 + threadIdx.x;
    if (idx >= COUT * KTOT) return;
    int cout = idx / KTOT, k = idx - cout * KTOT;
    int koct = k >> 3, j = k & 7;
    A16[((size_t)koct * COUT + cout) * 8 + j] = (_Float16)Kw[idx];
}

__global__ __launch_bounds__(256, 3)
void conv_igemm_f16_v2(const float* __restrict__ X,
                       const _Float16* __restrict__ A16,
                       float* __restrict__ Out)
{
    __shared__ __align__(16) _Float16 Bs[2][128 * LDR];
    __shared__ int koff[KTOT];

    const int t = threadIdx.x;

    for (int k = t; k < KTOT; k += 256) {
        int c = k / 9, r = k - c * 9;
        int kh = r / 3, kw = r - kh * 3;
        koff[k] = c * CH_STRIDE + kh * W + kw;
    }

    // XCD-bijective block swizzle (m204)
    const int nwg = gridDim.x;
    const int q8 = nwg >> 3, r8 = nwg & 7;
    const int xcd = blockIdx.x & 7, idx8 = blockIdx.x >> 3;
    const int bid = (xcd < r8 ? xcd * (q8 + 1) : r8 * (q8 + 1) + (xcd - r8) * q8) + idx8;
    const int spBase = bid * 128;

    // ---- B staging mapping: col = sp lane, ksub = which 32-of-64 k ----
    const int col  = t & 127;
    const int ksub = (t >> 7) * 32;
    const int spg  = spBase + col;
    const int nimg = spg / OSP;
    const int rsp  = spg - nimg * OSP;
    const int oh   = rsp / OW;
    const int ow   = rsp - oh * OW;
    const float* Xb = X + ((size_t)nimg * IMG_STRIDE + oh * W + ow);

    // ---- compute mapping (verified in v1): 4 waves 2x2, 32x32 frags ----
    const int lane  = t & 63;
    const int wv    = t >> 6;
    const int wr    = wv >> 1;         // cout half
    const int wc    = wv & 1;          // sp half
    const int frow  = lane & 31;
    const int khalf = lane >> 5;       // 0/1: 8-of-16 k
    const int brow  = (wc * 64 + frow) * LDR;   // fp16 units
    const size_t arow0 = (size_t)(wr * 64 + frow) * 8;       // lane's A row offset (x8 fp16)
    const size_t arow1 = (size_t)(wr * 64 + 32 + frow) * 8;

    f32x16 acc[2][2];
#pragma unroll
    for (int i = 0; i < 2; i++)
#pragma unroll
        for (int j = 0; j < 2; j++)
#pragma unroll
            for (int e = 0; e < 16; e++) acc[i][j][e] = 0.f;

    __syncthreads();   // koff ready

    float bR[32];

#define GATHER(KT)                                                             \
    {                                                                          \
        _Pragma("unroll")                                                      \
        for (int q = 0; q < 8; q++) {                                          \
            int4 kv = *reinterpret_cast<const int4*>(&koff[(KT) + ksub + 4 * q]); \
            bR[4 * q + 0] = Xb[kv.x];                                          \
            bR[4 * q + 1] = Xb[kv.y];                                          \
            bR[4 * q + 2] = Xb[kv.z];                                          \
            bR[4 * q + 3] = Xb[kv.w];                                          \
        }                                                                      \
    }

#define CVTWRITE(BUF)                                                          \
    {                                                                          \
        const int sidx = col * LDR + ksub;                                     \
        _Pragma("unroll")                                                      \
        for (int h = 0; h < 4; h++) {                                          \
            union { uint u[4]; f16x8 v; } pk;                                  \
            _Pragma("unroll")                                                  \
            for (int p = 0; p < 4; p++)                                        \
                pk.u[p] = pkrtz_u32(bR[8 * h + 2 * p], bR[8 * h + 2 * p + 1]); \
            *reinterpret_cast<f16x8*>(&Bs[BUF][sidx + 8 * h]) = pk.v;          \
        }                                                                      \
    }

#define MFMA_STEP(S, B)                                                        \
    {                                                                          \
        _Pragma("unroll")                                                      \
        for (int kk = 0; kk < 4; kk++) {                                       \
            const size_t abase = (size_t)((S) * 8 + kk * 2 + khalf) * (COUT * 8); \
            f16x8 a0 = *reinterpret_cast<const f16x8*>(&A16[abase + arow0]);   \
            f16x8 a1 = *reinterpret_cast<const f16x8*>(&A16[abase + arow1]);   \
            f16x8 b0 = *reinterpret_cast<const f16x8*>(&Bs[B][brow + kk * 16 + khalf * 8]); \
            f16x8 b1 = *reinterpret_cast<const f16x8*>(&Bs[B][brow + 32 * LDR + kk * 16 + khalf * 8]); \
            acc[0][0] = __builtin_amdgcn_mfma_f32_32x32x16_f16(a0, b0, acc[0][0], 0, 0, 0); \
            acc[0][1] = __builtin_amdgcn_mfma_f32_32x32x16_f16(a0, b1, acc[0][1], 0, 0, 0); \
            acc[1][0] = __builtin_amdgcn_mfma_f32_32x32x16_f16(a1, b0, acc[1][0], 0, 0, 0); \
            acc[1][1] = __builtin_amdgcn_mfma_f32_32x32x16_f16(a1, b1, acc[1][1], 0, 0, 0); \
        }                                                                      \
    }

    // ---- prologue: buf0 <- tile0; regs <- tile1 ----
    GATHER(0);
    CVTWRITE(0);
    GATHER(BK);
    __syncthreads();

    // ---- main loop: single barrier per step, dbuf ----
    // invariant at iter i: Bs[i&1] = tile i, bR = tile i+1
#pragma unroll 1
    for (int i = 0; i < NSTEP - 1; i++) {
        CVTWRITE((i + 1) & 1);                 // tile i+1 -> other buf
        if (i < NSTEP - 2) GATHER((i + 2) * BK); // tile i+2 -> regs
        MFMA_STEP(i, i & 1);                   // compute tile i
        __syncthreads();
    }
    MFMA_STEP(NSTEP - 1, (NSTEP - 1) & 1);     // tile 8 in buf0

#undef GATHER
#undef CVTWRITE
#undef MFMA_STEP

    // ---- store (verified in v1): D col=lane&31, row=(reg&3)+8*(reg>>2)+4*khalf ----
#pragma unroll
    for (int j = 0; j < 2; j++) {
        const int sp2 = spBase + wc * 64 + j * 32 + frow;
        const int n2  = sp2 / OSP;
        const int r2  = sp2 - n2 * OSP;
        float* Ob = Out + (size_t)n2 * (COUT * OSP) + r2;
#pragma unroll
        for (int i = 0; i < 2; i++) {
            const int cbase = wr * 64 + i * 32 + 4 * khalf;
#pragma unroll
            for (int reg = 0; reg < 16; reg++) {
                const int crow = cbase + (reg & 3) + 8 * (reg >> 2);
                Ob[(size_t)crow * OSP] = acc[i][j][reg];
            }
        }
    }
}

extern "C" void kernel_launch(void* const* d_in, const int* in_sizes, int n_in,
                              void* d_out, int out_size, void* d_ws, size_t ws_size,
                              hipStream_t stream) {
    const float* X  = (const float*)d_in[0];
    const float* Kw = (const float*)d_in[1];
    float* Out = (float*)d_out;
    _Float16* A16 = (_Float16*)d_ws;    // 147456 B needed

    prep_a<<<(COUT * KTOT + 255) / 256, 256, 0, stream>>>(Kw, A16);
    conv_igemm_f16_v2<<<SPTOT / 128, 256, 0, stream>>>(X, A16, Out);
}

// Round 7
// 141.797 us; speedup vs baseline: 5.1576x; 1.0254x over previous
//
#include <hip/hip_runtime.h>

// Conv2d 3x3 VALID (NCHW/OIHW, fp32) as implicit GEMM, fp16 MFMA, v3.
//   C[cout][sp] = sum_k A[cout][k]*B[k][sp], K=576, M=128, N=387200
// v2 (160us dispatch): all pipes <21%, Occupancy 31% (~2.5 waves/SIMD) ->
// latency-bound with nothing to co-schedule. v3: 512-thread blocks (8 waves),
// same 128x128xBK=64 tile; 16 gathers/thread; acc 32 VGPR; launch_bounds(512,6)
// -> target ~24 waves/CU for TLP latency hiding.

typedef __attribute__((ext_vector_type(8)))  _Float16 f16x8;
typedef __attribute__((ext_vector_type(16))) float    f32x16;

constexpr int C_IN = 64, H = 112, W = 112;
constexpr int COUT = 128, OH = 110, OW = 110;
constexpr int NIMG = 32;
constexpr int KTOT = C_IN * 9;          // 576
constexpr int OSP  = OH * OW;           // 12100
constexpr int SPTOT = NIMG * OSP;       // 387200 = 3025 * 128
constexpr int IMG_STRIDE = C_IN * H * W;
constexpr int CH_STRIDE  = H * W;       // 12544
constexpr int BK  = 64;
constexpr int NSTEP = KTOT / BK;        // 9
constexpr int LDR = 68;                 // fp16 units; 136B rows -> 2-way banks (free)

__device__ __forceinline__ uint pkrtz_u32(float lo, float hi) {
    union { __fp16 __attribute__((ext_vector_type(2))) h; uint u; } c;
    c.h = __builtin_amdgcn_cvt_pkrtz(lo, hi);
    return c.u;
}

// A16[koct][cout][j] = (f16)Kw[cout][koct*8+j]  (frag-native, 147KB, L2-resident)
__global__ void prep_a(const float* __restrict__ Kw, _Float16* __restrict__ A16) {
    int idx = blockIdx.x * 256 + threadIdx.x;
    if (idx >= COUT * KTOT) return;
    int cout = idx / KTOT, k = idx - cout * KTOT;
    int koct = k >> 3, j = k & 7;
    A16[((size_t)koct * COUT + cout) * 8 + j] = (_Float16)Kw[idx];
}

__global__ __launch_bounds__(512, 6)
void conv_igemm_f16_v3(const float* __restrict__ X,
                       const _Float16* __restrict__ A16,
                       float* __restrict__ Out)
{
    __shared__ __align__(16) _Float16 Bs[2][128 * LDR];
    __shared__ int koff[KTOT];

    const int t = threadIdx.x;

    for (int k = t; k < KTOT; k += 512) {
        int c = k / 9, r = k - c * 9;
        int kh = r / 3, kw = r - kh * 3;
        koff[k] = c * CH_STRIDE + kh * W + kw;
    }

    // XCD-bijective block swizzle (m204)
    const int nwg = gridDim.x;
    const int q8 = nwg >> 3, r8 = nwg & 7;
    const int xcd = blockIdx.x & 7, idx8 = blockIdx.x >> 3;
    const int bid = (xcd < r8 ? xcd * (q8 + 1) : r8 * (q8 + 1) + (xcd - r8) * q8) + idx8;
    const int spBase = bid * 128;

    // ---- B staging: col = t&127 (sp), kq16 = 16-k chunk per thread-group ----
    const int col  = t & 127;
    const int kq16 = (t >> 7) * 16;     // 0/16/32/48
    const int spg  = spBase + col;
    const int nimg = spg / OSP;
    const int rsp  = spg - nimg * OSP;
    const int oh   = rsp / OW;
    const int ow   = rsp - oh * OW;
    const float* Xb = X + ((size_t)nimg * IMG_STRIDE + oh * W + ow);

    // ---- compute mapping: 8 waves = 4 cout-quarters x 2 sp-halves ----
    const int lane  = t & 63;
    const int wv    = t >> 6;
    const int wq    = wv >> 1;          // 0..3: cout quarter (32 couts)
    const int wc    = wv & 1;           // 0/1: sp half (64 sp)
    const int frow  = lane & 31;
    const int khalf = lane >> 5;        // 0/1: 8-of-16 k
    const int brow  = (wc * 64 + frow) * LDR;
    const size_t arow = (size_t)(wq * 32 + frow) * 8;

    f32x16 acc[2];
#pragma unroll
    for (int j = 0; j < 2; j++)
#pragma unroll
        for (int e = 0; e < 16; e++) acc[j][e] = 0.f;

    __syncthreads();   // koff ready

    float bR[16];

#define GATHER(KT)                                                             \
    {                                                                          \
        _Pragma("unroll")                                                      \
        for (int q = 0; q < 4; q++) {                                          \
            int4 kv = *reinterpret_cast<const int4*>(&koff[(KT) + kq16 + 4 * q]); \
            bR[4 * q + 0] = Xb[kv.x];                                          \
            bR[4 * q + 1] = Xb[kv.y];                                          \
            bR[4 * q + 2] = Xb[kv.z];                                          \
            bR[4 * q + 3] = Xb[kv.w];                                          \
        }                                                                      \
    }

#define CVTWRITE(BUF)                                                          \
    {                                                                          \
        const int sidx = col * LDR + kq16;                                     \
        _Pragma("unroll")                                                      \
        for (int h = 0; h < 2; h++) {                                          \
            union { uint u[4]; f16x8 v; } pk;                                  \
            _Pragma("unroll")                                                  \
            for (int p = 0; p < 4; p++)                                        \
                pk.u[p] = pkrtz_u32(bR[8 * h + 2 * p], bR[8 * h + 2 * p + 1]); \
            *reinterpret_cast<f16x8*>(&Bs[BUF][sidx + 8 * h]) = pk.v;          \
        }                                                                      \
    }

#define MFMA_STEP(S, B)                                                        \
    {                                                                          \
        _Pragma("unroll")                                                      \
        for (int kk = 0; kk < 4; kk++) {                                       \
            const size_t abase = (size_t)((S) * 8 + kk * 2 + khalf) * (COUT * 8); \
            f16x8 a0 = *reinterpret_cast<const f16x8*>(&A16[abase + arow]);    \
            f16x8 b0 = *reinterpret_cast<const f16x8*>(&Bs[B][brow + kk * 16 + khalf * 8]); \
            f16x8 b1 = *reinterpret_cast<const f16x8*>(&Bs[B][brow + 32 * LDR + kk * 16 + khalf * 8]); \
            acc[0] = __builtin_amdgcn_mfma_f32_32x32x16_f16(a0, b0, acc[0], 0, 0, 0); \
            acc[1] = __builtin_amdgcn_mfma_f32_32x32x16_f16(a0, b1, acc[1], 0, 0, 0); \
        }                                                                      \
    }

    // ---- prologue: buf0 <- tile0; regs <- tile1 ----
    GATHER(0);
    CVTWRITE(0);
    GATHER(BK);
    __syncthreads();

    // ---- main loop: dbuf, single barrier/step ----
    // invariant at iter i: Bs[i&1] = tile i, bR = tile i+1
#pragma unroll 1
    for (int i = 0; i < NSTEP - 1; i++) {
        CVTWRITE((i + 1) & 1);
        if (i < NSTEP - 2) GATHER((i + 2) * BK);
        MFMA_STEP(i, i & 1);
        __syncthreads();
    }
    MFMA_STEP(NSTEP - 1, (NSTEP - 1) & 1);

#undef GATHER
#undef CVTWRITE
#undef MFMA_STEP

    // ---- store (verified mapping): D col=lane&31, row=(reg&3)+8*(reg>>2)+4*khalf ----
#pragma unroll
    for (int j = 0; j < 2; j++) {
        const int sp2 = spBase + wc * 64 + j * 32 + frow;
        const int n2  = sp2 / OSP;
        const int r2  = sp2 - n2 * OSP;
        float* Ob = Out + (size_t)n2 * (COUT * OSP) + r2;
        const int cbase = wq * 32 + 4 * khalf;
#pragma unroll
        for (int reg = 0; reg < 16; reg++) {
            const int crow = cbase + (reg & 3) + 8 * (reg >> 2);
            Ob[(size_t)crow * OSP] = acc[j][reg];
        }
    }
}

extern "C" void kernel_launch(void* const* d_in, const int* in_sizes, int n_in,
                              void* d_out, int out_size, void* d_ws, size_t ws_size,
                              hipStream_t stream) {
    const float* X  = (const float*)d_in[0];
    const float* Kw = (const float*)d_in[1];
    float* Out = (float*)d_out;
    _Float16* A16 = (_Float16*)d_ws;    // 147456 B

    prep_a<<<(COUT * KTOT + 255) / 256, 256, 0, stream>>>(Kw, A16);
    conv_igemm_f16_v3<<<SPTOT / 128, 512, 0, stream>>>(X, A16, Out);
}

// Round 8
// 111.572 us; speedup vs baseline: 6.5549x; 1.2709x over previous
//
#include <hip/hip_runtime.h>

// Conv2d 3x3 VALID (NCHW/OIHW, fp32), fp16 MFMA, v4 "shift-GEMM".
// Reformulation: C[cout][sp] = sum_{s=0..8} sum_{c=0..63} K[cout][c][s] * Xs[c][sp]
// where s=(kh,kw) and Xs is X shifted by (kh,kw). Per step s: B-tile is a DENSE
// shifted window of X -> staged with float2 row-loads (no gather, no koff),
// compile-time per-step offsets (full unroll). LDS [sp][c] c-minor, LDC=72 hw,
// per-row column XOR swizzle (bank-balanced, in-row bijective).
// v3-verified wave/frag/store mappings retained (8 waves = 4 cout-q x 2 sp-h).

typedef __attribute__((ext_vector_type(8)))  _Float16 f16x8;
typedef __attribute__((ext_vector_type(16))) float    f32x16;

struct __attribute__((aligned(4))) f2u { float x, y; };  // 4B-aligned pair load

constexpr int C_IN = 64, H = 112, W = 112;
constexpr int COUT = 128, OH = 110, OW = 110;
constexpr int NIMG = 32;
constexpr int KTOT = C_IN * 9;          // 576
constexpr int OSP  = OH * OW;           // 12100
constexpr int SPTOT = NIMG * OSP;       // 387200 = 3025 * 128
constexpr int IMG_STRIDE = C_IN * H * W;
constexpr int CH_STRIDE  = H * W;       // 12544
constexpr int LDC = 72;                 // halfwords/row: 144B rows, 16B-aligned

__device__ __forceinline__ uint pkrtz_u32(float lo, float hi) {
    union { __fp16 __attribute__((ext_vector_type(2))) h; uint u; } c;
    c.h = __builtin_amdgcn_cvt_pkrtz(lo, hi);
    return c.u;
}

// column-swizzled LDS halfword index (in-row bijective, bank-balanced)
__device__ __forceinline__ int swz(int row, int chw) {
    return row * LDC + (chw ^ (((row >> 1) & 7) << 3));
}

// A16[(s*8 + o)*COUT*8 + cout*8 + j] = (f16)Kw[cout][(o*8+j)*9 + s]
// (frag-native per shift s, octet o = 8 channels; 147KB, L2-resident)
__global__ void prep_a(const float* __restrict__ Kw, _Float16* __restrict__ A16) {
    int idx = blockIdx.x * 256 + threadIdx.x;
    if (idx >= COUT * KTOT) return;
    int cout = idx / KTOT, k = idx - cout * KTOT;
    int c = k / 9, s = k - c * 9;
    int o = c >> 3, j = c & 7;
    A16[((size_t)(s * 8 + o) * COUT + cout) * 8 + j] = (_Float16)Kw[idx];
}

__global__ __launch_bounds__(512, 4)
void conv_shift_f16(const float* __restrict__ X,
                    const _Float16* __restrict__ A16,
                    float* __restrict__ Out)
{
    __shared__ __align__(16) _Float16 Bs[2][128 * LDC];

    const int t = threadIdx.x;

    // XCD-bijective block swizzle (m204)
    const int nwg = gridDim.x;
    const int q8 = nwg >> 3, r8 = nwg & 7;
    const int xcd = blockIdx.x & 7, idx8 = blockIdx.x >> 3;
    const int bid = (xcd < r8 ? xcd * (q8 + 1) : r8 * (q8 + 1) + (xcd - r8) * q8) + idx8;
    const int spBase = bid * 128;

    // ---- staging: spp = sp-pair (2 consecutive sp, always row-interior since
    //      OW=110 even & pairs even-aligned), c0 = 8-channel group ----
    const int spp = t & 63;
    const int c0  = (t >> 6) << 3;
    const int sp0 = spBase + 2 * spp;
    const int nimg = sp0 / OSP;
    const int rsp  = sp0 - nimg * OSP;
    const int oh   = rsp / OW;
    const int ow   = rsp - oh * OW;
    const float* Xr = X + ((size_t)nimg * IMG_STRIDE + (size_t)c0 * CH_STRIDE + oh * W + ow);
    const int whw0 = swz(2 * spp,     c0);   // row for .x values
    const int whw1 = swz(2 * spp + 1, c0);   // row for .y values

    // ---- compute mapping (v3-verified): 8 waves = 4 cout-quarters x 2 sp-halves ----
    const int lane  = t & 63;
    const int wv    = t >> 6;
    const int wq    = wv >> 1;          // 0..3: cout quarter (32 couts)
    const int wc    = wv & 1;           // 0/1: sp half (64 sp)
    const int frow  = lane & 31;
    const int khalf = lane >> 5;        // 0/1: 8-of-16 k
    const size_t arow = (size_t)(wq * 32 + frow) * 8;
    const int bmask = ((frow >> 1) & 7) << 3;   // read-side column xor (same for both 32-sp blocks)
    const int brw0  = (wc * 64 + frow) * LDC;
    const int brw1  = (wc * 64 + 32 + frow) * LDC;

    f32x16 acc[2];
#pragma unroll
    for (int j = 0; j < 2; j++)
#pragma unroll
        for (int e = 0; e < 16; e++) acc[j][e] = 0.f;

    f2u g[8];

#define SOFF(S) (((S) / 3) * W + ((S) % 3))

#define GATHER(S)                                                              \
    {                                                                          \
        _Pragma("unroll")                                                      \
        for (int j = 0; j < 8; j++)                                            \
            g[j] = *reinterpret_cast<const f2u*>(Xr + (size_t)j * CH_STRIDE + SOFF(S)); \
    }

#define CVTWRITE(BUF)                                                          \
    {                                                                          \
        union { uint u[4]; f16x8 v; } px, py;                                  \
        _Pragma("unroll")                                                      \
        for (int p = 0; p < 4; p++) {                                          \
            px.u[p] = pkrtz_u32(g[2 * p].x, g[2 * p + 1].x);                   \
            py.u[p] = pkrtz_u32(g[2 * p].y, g[2 * p + 1].y);                   \
        }                                                                      \
        *reinterpret_cast<f16x8*>(&Bs[BUF][whw0]) = px.v;                      \
        *reinterpret_cast<f16x8*>(&Bs[BUF][whw1]) = py.v;                      \
    }

#define MFMA_STEP(S, B)                                                        \
    {                                                                          \
        _Pragma("unroll")                                                      \
        for (int kk = 0; kk < 4; kk++) {                                       \
            const size_t abase = (size_t)((S) * 8 + kk * 2 + khalf) * (COUT * 8) + arow; \
            const int chw = (kk * 16 + khalf * 8) ^ bmask;                     \
            f16x8 a0 = *reinterpret_cast<const f16x8*>(&A16[abase]);           \
            f16x8 b0 = *reinterpret_cast<const f16x8*>(&Bs[B][brw0 + chw]);    \
            f16x8 b1 = *reinterpret_cast<const f16x8*>(&Bs[B][brw1 + chw]);    \
            acc[0] = __builtin_amdgcn_mfma_f32_32x32x16_f16(a0, b0, acc[0], 0, 0, 0); \
            acc[1] = __builtin_amdgcn_mfma_f32_32x32x16_f16(a0, b1, acc[1], 0, 0, 0); \
        }                                                                      \
    }

    // ---- prologue: buf0 <- shift0; regs <- shift1 ----
    GATHER(0);
    CVTWRITE(0);
    GATHER(1);
    __syncthreads();

    // ---- main loop: 9 shift-steps, full unroll (compile-time offsets), dbuf ----
    // invariant at iter s: Bs[s&1] = shift s, g = shift s+1
#pragma unroll
    for (int s = 0; s < 9; s++) {
        if (s < 8) CVTWRITE((s + 1) & 1);
        if (s < 7) GATHER(s + 2);
        MFMA_STEP(s, s & 1);
        __syncthreads();
    }

#undef GATHER
#undef CVTWRITE
#undef MFMA_STEP
#undef SOFF

    // ---- store (v3-verified): D col=lane&31, row=(reg&3)+8*(reg>>2)+4*khalf ----
#pragma unroll
    for (int j = 0; j < 2; j++) {
        const int sp2 = spBase + wc * 64 + j * 32 + frow;
        const int n2  = sp2 / OSP;
        const int r2  = sp2 - n2 * OSP;
        float* Ob = Out + (size_t)n2 * (COUT * OSP) + r2;
        const int cbase = wq * 32 + 4 * khalf;
#pragma unroll
        for (int reg = 0; reg < 16; reg++) {
            const int crow = cbase + (reg & 3) + 8 * (reg >> 2);
            Ob[(size_t)crow * OSP] = acc[j][reg];
        }
    }
}

extern "C" void kernel_launch(void* const* d_in, const int* in_sizes, int n_in,
                              void* d_out, int out_size, void* d_ws, size_t ws_size,
                              hipStream_t stream) {
    const float* X  = (const float*)d_in[0];
    const float* Kw = (const float*)d_in[1];
    float* Out = (float*)d_out;
    _Float16* A16 = (_Float16*)d_ws;    // 147456 B

    prep_a<<<(COUT * KTOT + 255) / 256, 256, 0, stream>>>(Kw, A16);
    conv_shift_f16<<<SPTOT / 128, 512, 0, stream>>>(X, A16, Out);
}